// Round 3
// baseline (320.817 us; speedup 1.0000x reference)
//
#include <hip/hip_runtime.h>

// DarkChannel: cmin over C=3, then 15x15 min erosion, +inf border.
// Round 3: TY=30 (two van Herk groups per block). Register blocks A/B/C of
// 15 rows x float4; channel-major accumulate loads (15 independent loads per
// batch). Group-1 loads issued before group-0 phase2 to overlap. LDS single
// 15x1040 buffer (62.4 KB -> 2 blocks/CU). Read amplification 45/30 = 1.5x
// (was 29/15 = 1.93x).

#define IMG_H 1024
#define IMG_W 1024
#define IMG_C 3
#define IMG_B 16
#define GY    15     // van Herk group = window size
#define TY    30     // output rows per block (2 groups)
#define NT    256
#define LROW  1040   // 8 INF guard + 1024 + 8 INF guard
#define RAD   7

__device__ __forceinline__ float4 min4(float4 a, float4 b) {
    return make_float4(fminf(a.x, b.x), fminf(a.y, b.y),
                       fminf(a.z, b.z), fminf(a.w, b.w));
}

// Load 15 rows (base..base+14) of channel-min at column cx, channel-major so
// each batch of 15 loads is independent. OOB rows -> clamped address + INF.
__device__ __forceinline__ void load_block(const float* __restrict__ imgb,
                                           size_t plane, int base, int cx,
                                           float4* dst) {
#pragma unroll
    for (int i = 0; i < GY; ++i) {
        int yc = min(max(base + i, 0), IMG_H - 1);
        dst[i] = *(const float4*)(imgb + (size_t)yc * IMG_W + cx);
    }
#pragma unroll
    for (int c = 1; c < IMG_C; ++c) {
#pragma unroll
        for (int i = 0; i < GY; ++i) {
            int yc = min(max(base + i, 0), IMG_H - 1);
            float4 v = *(const float4*)(imgb + (size_t)c * plane +
                                        (size_t)yc * IMG_W + cx);
            dst[i] = min4(dst[i], v);
        }
    }
    const float INF = __builtin_inff();
    const float4 INF4 = make_float4(INF, INF, INF, INF);
#pragma unroll
    for (int i = 0; i < GY; ++i)
        if ((unsigned)(base + i) >= IMG_H) dst[i] = INF4;
}

// Vertical window mins for one group: suffix over cur (clobbers cur -- pass
// the block that dies), prefix from nxt, write 15 LDS rows.
__device__ __forceinline__ void store_vmin(float4* cur, const float4* nxt,
                                           float (*vmin)[LROW], int cx) {
#pragma unroll
    for (int i = GY - 2; i >= 0; --i) cur[i] = min4(cur[i], cur[i + 1]);
    *(float4*)&vmin[0][8 + cx] = cur[0];
    float4 p = nxt[0];
#pragma unroll
    for (int i = 1; i < GY; ++i) {
        *(float4*)&vmin[i][8 + cx] = min4(cur[i], p);
        if (i < GY - 1) p = min4(p, nxt[i]);
    }
}

// Horizontal 15-min from guarded LDS rows; coalesced float4 stores.
__device__ __forceinline__ void phase2(const float (*vmin)[LROW],
                                       float* __restrict__ outb,
                                       int ybase, int rows, int cx) {
    for (int r = 0; r < rows; ++r) {
        const float* row = &vmin[r][0];
        float4 a  = *(const float4*)(row + cx);        // w0..w3
        float4 bb = *(const float4*)(row + cx + 4);    // w4..w7
        float4 cc = *(const float4*)(row + cx + 8);    // w8..w11
        float4 dd = *(const float4*)(row + cx + 12);   // w12..w15
        float4 ee = *(const float4*)(row + cx + 16);   // w16..w19
        float4 m = min4(min4(bb, cc), dd);
        float core = fminf(fminf(m.x, m.y), fminf(m.z, m.w));
        float4 o;
        o.x = fminf(core, fminf(a.y, fminf(a.z, a.w)));    // w[1..15]
        o.y = fminf(core, fminf(a.z, fminf(a.w, ee.x)));   // w[2..16]
        o.z = fminf(core, fminf(a.w, fminf(ee.x, ee.y)));  // w[3..17]
        o.w = fminf(core, fminf(ee.x, fminf(ee.y, ee.z))); // w[4..18]
        *(float4*)(outb + (size_t)(ybase + r) * IMG_W + cx) = o;
    }
}

__global__ __launch_bounds__(NT, 2)
void DarkChannel_77713138254515_kernel(const float* __restrict__ img,
                                       float* __restrict__ out) {
    __shared__ float vmin[GY][LROW];

    const int t  = threadIdx.x;
    const int y0 = blockIdx.x * TY;
    const int b  = blockIdx.y;
    const int cx = 4 * t;

    const size_t plane = (size_t)IMG_H * IMG_W;
    const float* imgb = img + (size_t)b * IMG_C * plane;
    float* outb = out + (size_t)b * plane;

    // +/-8 column INF guards (written once; never overwritten by vmin rows)
    if (t < GY * 16) {
        int r = t >> 4, c = t & 15;
        int col = (c < 8) ? c : (IMG_W + c);
        vmin[r][col] = __builtin_inff();
    }

    float4 A[GY], B[GY], C[GY];
    load_block(imgb, plane, y0 - RAD,          cx, A);   // rows y0-7 .. y0+7
    load_block(imgb, plane, y0 - RAD + GY,     cx, B);   // rows y0+8 .. y0+22

    store_vmin(A, B, vmin, cx);                          // group 0 (A dies)

    load_block(imgb, plane, y0 - RAD + 2 * GY, cx, C);   // rows y0+23.. issued
                                                         // before phase2 g0
    __syncthreads();
    phase2(vmin, outb, y0, min(GY, IMG_H - y0), cx);
    __syncthreads();

    store_vmin(B, C, vmin, cx);                          // group 1 (B dies)

    __syncthreads();
    phase2(vmin, outb, y0 + GY, min(GY, IMG_H - (y0 + GY)), cx);
}

extern "C" void kernel_launch(void* const* d_in, const int* in_sizes, int n_in,
                              void* d_out, int out_size, void* d_ws, size_t ws_size,
                              hipStream_t stream) {
    const float* img = (const float*)d_in[0];
    float* out = (float*)d_out;

    dim3 grid((IMG_H + TY - 1) / TY,   // 35 y-tiles
              IMG_B);                  // 16
    DarkChannel_77713138254515_kernel<<<grid, dim3(NT), 0, stream>>>(img, out);
}

// Round 4
// 308.523 us; speedup vs baseline: 1.0398x; 1.0398x over previous
//
#include <hip/hip_runtime.h>

// DarkChannel: cmin over C=3, then 15x15 min erosion, +inf border.
// Round 4: (a) TY=32 -> grid 32x16 = 512 blocks = exactly 2 blocks/CU
// resident -> ONE generation, no straggler tail (round-3 had 560 blocks ->
// 48-block tail at 9% occupancy = half the runtime). (b) all LDS traffic as
// float2 (b64): round-3's b128 accesses showed 7.1M SQ_LDS_BANK_CONFLICT
// (4-way word-phased); 2-way b64 aliasing is free (m136).
// Structure: van Herk groups G0..G2 (15 rows each) + 1-row G3; outputs
// 30..31 from C-suffix + G3 row. LDS vmin[15][1040] = 62.4 KB -> 2 blk/CU.

#define IMG_H 1024
#define IMG_W 1024
#define IMG_C 3
#define IMG_B 16
#define GY    15     // van Herk group = window size
#define TY    32     // output rows per block
#define NT    256
#define LROW  1040   // 8 INF guard + 1024 + 8 INF guard
#define RAD   7

__device__ __forceinline__ float4 min4(float4 a, float4 b) {
    return make_float4(fminf(a.x, b.x), fminf(a.y, b.y),
                       fminf(a.z, b.z), fminf(a.w, b.w));
}

// Load 15 rows (base..base+14) of channel-min at column cx, channel-major so
// each batch of 15 loads is independent. OOB rows -> clamped address + INF.
__device__ __forceinline__ void load_block(const float* __restrict__ imgb,
                                           size_t plane, int base, int cx,
                                           float4* dst) {
#pragma unroll
    for (int i = 0; i < GY; ++i) {
        int yc = min(max(base + i, 0), IMG_H - 1);
        dst[i] = *(const float4*)(imgb + (size_t)yc * IMG_W + cx);
    }
#pragma unroll
    for (int c = 1; c < IMG_C; ++c) {
#pragma unroll
        for (int i = 0; i < GY; ++i) {
            int yc = min(max(base + i, 0), IMG_H - 1);
            float4 v = *(const float4*)(imgb + (size_t)c * plane +
                                        (size_t)yc * IMG_W + cx);
            dst[i] = min4(dst[i], v);
        }
    }
    const float INF = __builtin_inff();
    const float4 INF4 = make_float4(INF, INF, INF, INF);
#pragma unroll
    for (int i = 0; i < GY; ++i)
        if ((unsigned)(base + i) >= IMG_H) dst[i] = INF4;
}

__device__ __forceinline__ void lds_store4(float (*vmin)[LROW], int r, int cx,
                                           float4 v) {
    // two b64 stores (2-way bank aliasing = free; b128 was 4-way conflicted)
    *(float2*)&vmin[r][8 + cx]     = make_float2(v.x, v.y);
    *(float2*)&vmin[r][8 + cx + 2] = make_float2(v.z, v.w);
}

// Vertical window mins for one group: suffix over cur (clobbers cur), prefix
// from nxt, write 15 LDS rows.
__device__ __forceinline__ void store_vmin(float4* cur, const float4* nxt,
                                           float (*vmin)[LROW], int cx) {
#pragma unroll
    for (int i = GY - 2; i >= 0; --i) cur[i] = min4(cur[i], cur[i + 1]);
    lds_store4(vmin, 0, cx, cur[0]);
    float4 p = nxt[0];
#pragma unroll
    for (int i = 1; i < GY; ++i) {
        lds_store4(vmin, i, cx, min4(cur[i], p));
        if (i < GY - 1) p = min4(p, nxt[i]);
    }
}

// Horizontal 15-min from guarded LDS rows via float2 reads; float4 stores.
__device__ __forceinline__ void phase2(const float (*vmin)[LROW],
                                       float* __restrict__ outb,
                                       int ybase, int rows, int cx) {
    for (int r = 0; r < rows; ++r) {
        const float* row = &vmin[r][0];
        // w[k] = img col (cx-8+k), k=0..19  -> floats row[cx .. cx+19]
        float2 P[10];
#pragma unroll
        for (int k = 0; k < 10; ++k) P[k] = *(const float2*)(row + cx + 2 * k);
        // core = min w[4..15] = min over P2..P7
        float2 m2 = P[2];
#pragma unroll
        for (int k = 3; k <= 7; ++k) {
            m2.x = fminf(m2.x, P[k].x); m2.y = fminf(m2.y, P[k].y);
        }
        float core = fminf(m2.x, m2.y);
        float4 o;
        o.x = fminf(core, fminf(P[0].y, fminf(P[1].x, P[1].y))); // w[1..15]
        o.y = fminf(core, fminf(P[1].x, fminf(P[1].y, P[8].x))); // w[2..16]
        o.z = fminf(core, fminf(P[1].y, fminf(P[8].x, P[8].y))); // w[3..17]
        o.w = fminf(core, fminf(P[8].x, fminf(P[8].y, P[9].x))); // w[4..18]
        *(float4*)(outb + (size_t)(ybase + r) * IMG_W + cx) = o;
    }
}

__global__ __launch_bounds__(NT, 2)
void DarkChannel_77713138254515_kernel(const float* __restrict__ img,
                                       float* __restrict__ out) {
    __shared__ float vmin[GY][LROW];

    const int t  = threadIdx.x;
    const int y0 = blockIdx.x * TY;
    const int b  = blockIdx.y;
    const int cx = 4 * t;

    const size_t plane = (size_t)IMG_H * IMG_W;
    const float* imgb = img + (size_t)b * IMG_C * plane;
    float* outb = out + (size_t)b * plane;

    // +/-8 column INF guards (written once; never overwritten)
    if (t < GY * 16) {
        int r = t >> 4, c = t & 15;
        int col = (c < 8) ? c : (IMG_W + c);
        vmin[r][col] = __builtin_inff();
    }

    float4 A[GY], B[GY], C[GY];
    load_block(imgb, plane, y0 - RAD,          cx, A);   // rows y0-7 .. y0+7
    load_block(imgb, plane, y0 - RAD + GY,     cx, B);   // rows y0+8 .. y0+22

    store_vmin(A, B, vmin, cx);                          // group 0 (A dies)

    load_block(imgb, plane, y0 - RAD + 2 * GY, cx, C);   // rows y0+23..y0+37

    // G3: single extra row y0+38 (for output row 31)
    float4 g3;
    {
        int y = y0 + 38;
        int yc = min(y, IMG_H - 1);
        const float* p0 = imgb + (size_t)yc * IMG_W + cx;
        float4 v = min4(*(const float4*)p0,
                        min4(*(const float4*)(p0 + plane),
                             *(const float4*)(p0 + 2 * plane)));
        const float INF = __builtin_inff();
        g3 = (y < IMG_H) ? v : make_float4(INF, INF, INF, INF);
    }

    __syncthreads();
    phase2(vmin, outb, y0, GY, cx);                      // out rows 0..14
    __syncthreads();

    store_vmin(B, C, vmin, cx);                          // group 1 (B dies)

    __syncthreads();
    phase2(vmin, outb, y0 + GY, GY, cx);                 // out rows 15..29
    __syncthreads();

    // outputs 30,31: suffix mins of C (+ g3 for row 31)
    {
        float4 s;                                        // running suffix of C
        s = C[GY - 1];
#pragma unroll
        for (int i = GY - 2; i >= 1; --i) s = min4(C[i], s);
        lds_store4(vmin, 1, cx, min4(s, g3));            // rows 24..38
        s = min4(C[0], s);
        lds_store4(vmin, 0, cx, s);                      // rows 23..37
    }
    __syncthreads();
    phase2(vmin, outb, y0 + 2 * GY, 2, cx);              // out rows 30,31
}

extern "C" void kernel_launch(void* const* d_in, const int* in_sizes, int n_in,
                              void* d_out, int out_size, void* d_ws, size_t ws_size,
                              hipStream_t stream) {
    const float* img = (const float*)d_in[0];
    float* out = (float*)d_out;

    dim3 grid(IMG_H / TY,   // 32 y-tiles
              IMG_B);       // 16  -> 512 blocks = 2/CU, one generation
    DarkChannel_77713138254515_kernel<<<grid, dim3(NT), 0, stream>>>(img, out);
}

// Round 5
// 297.834 us; speedup vs baseline: 1.0772x; 1.0359x over previous
//
#include <hip/hip_runtime.h>

// DarkChannel: cmin over C=3, then 15x15 min erosion, +inf border.
// Round 5: latency/TLP restructure. x split into 4 tiles of 256 cols.
//  stage : 30 rows x 272 cols of channel-min -> LDS, as 2040 INDEPENDENT
//          float4-triplet tasks (~8/thread) -> deep load batching.
//  vert  : van Herk per LDS column (stride-1 b32, conflict-free), in place.
//  horiz : 15-min per 4-col chunk from LDS, coalesced float4 stores.
// LDS 31.9 KB, launch_bounds(256,4) -> 4 blocks/CU = 16 waves/CU (2x TLP).
// Grid 4*64*16 = 4096 = exactly 4 generations at 4 blocks/CU; TY=16 means
// zero output-side bounds checks anywhere.

#define IMG_H 1024
#define IMG_W 1024
#define IMG_C 3
#define IMG_B 16
#define TY    16              // output rows per block
#define TX    256             // output cols per block
#define HALO  8
#define BW    (TX + 2*HALO)   // 272 staged cols
#define ROWS  (TY + 14)       // 30 staged rows
#define NCH   (BW / 4)        // 68 float4 chunks per row
#define NT    256
#define RAD   7

__device__ __forceinline__ float4 min4(float4 a, float4 b) {
    return make_float4(fminf(a.x, b.x), fminf(a.y, b.y),
                       fminf(a.z, b.z), fminf(a.w, b.w));
}

__global__ __launch_bounds__(NT, 4)
void DarkChannel_77713138254515_kernel(const float* __restrict__ img,
                                       float* __restrict__ out) {
    __shared__ float buf[ROWS][BW];          // 30*272*4 = 31.9 KB

    const int t  = threadIdx.x;
    const int x0 = blockIdx.x * TX;
    const int y0 = blockIdx.y * TY;
    const int b  = blockIdx.z;

    const size_t plane = (size_t)IMG_H * IMG_W;
    const float* imgb = img + (size_t)b * IMG_C * plane;
    float* outb = out + (size_t)b * plane;
    const float INF = __builtin_inff();
    const float4 INF4 = make_float4(INF, INF, INF, INF);

    // ---- stage: 30 rows x 68 chunks = 2040 independent tasks ----
#pragma unroll
    for (int k = 0; k < 8; ++k) {
        int task = t + NT * k;
        if (task < ROWS * NCH) {
            int r  = task / NCH;             // constant div -> magic mul
            int ch = task - r * NCH;
            int y  = y0 - RAD + r;
            int gx = x0 - HALO + 4 * ch;     // 4-aligned
            bool ok = ((unsigned)y < IMG_H) & ((unsigned)gx <= IMG_W - 4);
            int yc  = min(max(y, 0), IMG_H - 1);
            int gxc = min(max(gx, 0), IMG_W - 4);
            const float* p0 = imgb + (size_t)yc * IMG_W + gxc;
            float4 v0 = *(const float4*)(p0);
            float4 v1 = *(const float4*)(p0 + plane);
            float4 v2 = *(const float4*)(p0 + 2 * plane);
            float4 v  = min4(v0, min4(v1, v2));
            if (!ok) v = INF4;
            *(float4*)&buf[r][4 * ch] = v;   // row stride 1088B: 16B-aligned
        }
    }
    __syncthreads();

    // ---- vertical: van Herk per column, in place (stride-1 b32, no conflicts)
    for (int c = t; c < BW; c += NT) {       // t, and 256+t for t<16
        float col[ROWS];
#pragma unroll
        for (int r = 0; r < ROWS; ++r) col[r] = buf[r][c];
        // out[i] = min(col[i..i+14]), i = 0..15
        float S[15];                         // suffix over col[0..14]
        S[14] = col[14];
#pragma unroll
        for (int i = 13; i >= 0; --i) S[i] = fminf(col[i], S[i + 1]);
        buf[0][c] = S[0];
        float p = col[15];                   // prefix over col[15..29]
#pragma unroll
        for (int i = 1; i < 15; ++i) {
            buf[i][c] = fminf(S[i], p);
            p = fminf(p, col[15 + i]);
        }
        buf[15][c] = p;                      // min(col[15..29])
    }
    __syncthreads();

    // ---- horizontal: 16 rows x 64 chunks = 1024 tasks, exactly 4/thread ----
#pragma unroll
    for (int k = 0; k < 4; ++k) {
        int task = t + NT * k;
        int r  = task >> 6;
        int ch = task & 63;
        const float* row = &buf[r][4 * ch];  // buf col 4ch <-> img col x0-8+4ch
        float2 P[10];
#pragma unroll
        for (int j = 0; j < 10; ++j) P[j] = *(const float2*)(row + 2 * j);
        float2 m2 = P[2];                    // core = min w[4..15] = P2..P7
#pragma unroll
        for (int j = 3; j <= 7; ++j) {
            m2.x = fminf(m2.x, P[j].x); m2.y = fminf(m2.y, P[j].y);
        }
        float core = fminf(m2.x, m2.y);
        float4 o;
        o.x = fminf(core, fminf(P[0].y, fminf(P[1].x, P[1].y))); // w[1..15]
        o.y = fminf(core, fminf(P[1].x, fminf(P[1].y, P[8].x))); // w[2..16]
        o.z = fminf(core, fminf(P[1].y, fminf(P[8].x, P[8].y))); // w[3..17]
        o.w = fminf(core, fminf(P[8].x, fminf(P[8].y, P[9].x))); // w[4..18]
        *(float4*)(outb + (size_t)(y0 + r) * IMG_W + x0 + 4 * ch) = o;
    }
}

extern "C" void kernel_launch(void* const* d_in, const int* in_sizes, int n_in,
                              void* d_out, int out_size, void* d_ws, size_t ws_size,
                              hipStream_t stream) {
    const float* img = (const float*)d_in[0];
    float* out = (float*)d_out;

    dim3 grid(IMG_W / TX,   // 4
              IMG_H / TY,   // 64
              IMG_B);       // 16 -> 4096 blocks = 4 gens at 4 blocks/CU
    DarkChannel_77713138254515_kernel<<<grid, dim3(NT), 0, stream>>>(img, out);
}